// Round 1
// 358.477 us; speedup vs baseline: 1.0373x; 1.0373x over previous
//
#include <hip/hip_runtime.h>
#include <stdint.h>

// ---------------------------------------------------------------------------
// Attention_18116172054662 on MI355X (gfx950)
//   L = tgt @ src^T  (2-term split-f16: (tgt_hi + tgt_lo) @ src_f16)
//   weight = softmax(L, axis=tgt)   -> second output (f32, in place in d_out)
//   out = weight @ PT^T + Q + b  where  PT = W1 @ src^T,  Q = tgt @ W2^T
// R1: global_load_lds width-16 staging, fused column stats, vectorized EW.
// R2: XOR swizzle on 32-wide tiles (neutral there -> dropped for logits).
// R3: explicit dbuf (regressed, reverted).  R5: all-f16 pipeline.
// R6: algebraic restructure (PT/Q/final), BK=64 GEMMs.
// R7: BK=64 tiles have 128B row stride == full bank wrap -> ~16-way phase
//     conflicts. XOR chunk swizzle (slot = chunk ^ (row&7)) in BK=64 kernels.
// R8: logits GEMM rebuilt on the 256x256 / 8-wave / dbuf-prefetch template:
//     - single raw s_barrier per K-tile, no vmcnt drain in the hot loop
//       (prefetch for tile t+1 issued right after the barrier of tile t;
//       vmcnt(0) at tile t+1 start waits loads that had a full tile to land)
//     - paired-row LDS layout [128][64] + XOR chunk swizzle -> 2-way (free)
//       bank access on ds_read_b128 (was 8-way on the 64B-row BK=32 tiles)
//     - wave tile 64x128 (acc[4][8]) -> 250 B LDS per MFMA (was 375)
//     - s_setprio(1) around MFMA clusters (8 waves -> role split exists)
// ---------------------------------------------------------------------------

#define B_   4
#define S_   2048
#define D_   1024
#define OUTD 1024

typedef unsigned short ushort_t;
typedef _Float16 half8 __attribute__((ext_vector_type(8)));
typedef float    f32x4 __attribute__((ext_vector_type(4)));

__device__ __forceinline__ ushort_t f2h(float f) {
    union { _Float16 h; ushort_t u; } v;
    v.h = (_Float16)f;                    // RNE
    return v.u;
}
__device__ __forceinline__ float h2f(ushort_t u) {
    union { _Float16 h; ushort_t u; } v;
    v.u = u;
    return (float)v.h;
}

// async global->LDS, 16B per lane; LDS dest = wave-uniform base + lane*16
__device__ __forceinline__ void ld16(const ushort_t* g, ushort_t* l) {
    __builtin_amdgcn_global_load_lds(
        (const __attribute__((address_space(1))) void*)g,
        (__attribute__((address_space(3))) void*)l, 16, 0, 0);
}

// --------------------------- elementwise prep ------------------------------

// src -> f16; tgt -> f16 hi + f16 lo
__global__ void k_split(const float4* __restrict__ src, const float4* __restrict__ tgt,
                        ushort4* __restrict__ sh,
                        ushort4* __restrict__ th, ushort4* __restrict__ tl)
{
    const int64_t n4 = (int64_t)B_ * S_ * D_ / 4;
    for (int64_t i = (int64_t)blockIdx.x * blockDim.x + threadIdx.x; i < n4;
         i += (int64_t)gridDim.x * blockDim.x) {
        float4 s = src[i];
        sh[i] = (ushort4){f2h(s.x), f2h(s.y), f2h(s.z), f2h(s.w)};
        float4 tv = tgt[i];
        ushort4 ht = {f2h(tv.x), f2h(tv.y), f2h(tv.z), f2h(tv.w)};
        th[i] = ht;
        tl[i] = (ushort4){f2h(tv.x - h2f(ht.x)), f2h(tv.y - h2f(ht.y)),
                          f2h(tv.z - h2f(ht.z)), f2h(tv.w - h2f(ht.w))};
    }
}

__global__ void k_wconv(const float4* __restrict__ W, ushort4* __restrict__ wb)
{
    const int64_t n4 = (int64_t)OUTD * 2 * D_ / 4;
    for (int64_t i = (int64_t)blockIdx.x * blockDim.x + threadIdx.x; i < n4;
         i += (int64_t)gridDim.x * blockDim.x) {
        float4 w = W[i];
        wb[i] = (ushort4){f2h(w.x), f2h(w.y), f2h(w.z), f2h(w.w)};
    }
}

// ------------------------------- GEMM 1 ------------------------------------
// L[b] = tgt[b] @ src[b]^T, 2-term f16 split:  Ah*B + Al*B
// 256x256 tile, BK=32, 8 waves 4x2 of 64x128, 16x16x32 f16 MFMA.
// Double-buffered LDS, 1 s_barrier per K-tile, prefetch 1 tile deep.
// LDS layout per 256x32 tile: paired rows -> [128][64] f16, 128B lines,
//   chunk_g = (r&1)*4 + (k>>3); slot = chunk_g ^ ((r>>1)&7); 16B chunks.
// Epilogue: per-block (256-row chunk) column max/sumexp -> pm/ps (8 chunks).
__launch_bounds__(512, 2)
__global__ void k_gemm_logits(const ushort_t* __restrict__ Ah, const ushort_t* __restrict__ Al,
                              const ushort_t* __restrict__ Bs,
                              float* __restrict__ C,
                              float* __restrict__ pm, float* __restrict__ ps)
{
    const int M = S_, N = S_, K = D_;
    int b = blockIdx.z;
    Ah += (int64_t)b * M * K;  Al += (int64_t)b * M * K;
    Bs += (int64_t)b * N * K;
    C  += (int64_t)b * M * N;

    // dbuf: [2] x { Ah 16KB | Al 16KB | B 16KB }  (ushort units; 96 KiB total)
    __shared__ __align__(16) ushort_t lds[2 * 24576];
    __shared__ float red_m[4][256], red_s[4][256];

    int t    = threadIdx.x;                 // 0..511
    int m0   = blockIdx.y * 256, n0 = blockIdx.x * 256;
    int wave = t >> 6, lane = t & 63;
    int wr   = (wave >> 1) * 64;            // 0,64,128,192
    int wc   = (wave & 1) * 128;            // 0,128
    int l15  = lane & 15, quad = lane >> 4;

    f32x4 acc[4][8];
#pragma unroll
    for (int i = 0; i < 4; i++)
#pragma unroll
        for (int j = 0; j < 8; j++) acc[i][j] = (f32x4){0.f, 0.f, 0.f, 0.f};

    // ---- staging map: thread t writes LDS bytes [t*16, t*16+16) of each
    //      8KB pass (pass covers 64 paired-rows = 128 global rows).
    //      Invert the swizzle on the GLOBAL side; LDS dest stays linear.
    int pr   = t >> 3;                      // paired-row 0..63 within pass
    int slot = t & 7;
    int cg   = slot ^ (pr & 7);
    int srow = pr * 2 + (cg >> 2);          // 0..127 (+128 for pass 1)
    int scol = (cg & 3) * 8;                // f16 col within BK=32

    const ushort_t* gAh = Ah + (int64_t)(m0 + srow) * K + scol;
    const ushort_t* gAl = Al + (int64_t)(m0 + srow) * K + scol;
    const ushort_t* gB  = Bs + (int64_t)(n0 + srow) * K + scol;
    const int64_t rstep = (int64_t)128 * K;     // pass-1 global row offset

    auto stage = [&](int bufi, int kofs) {
        ushort_t* Lb = lds + bufi * 24576 + t * 8;
        ld16(gAh + kofs,         Lb);
        ld16(gAh + rstep + kofs, Lb + 4096);
        ld16(gAl + kofs,         Lb + 8192);
        ld16(gAl + rstep + kofs, Lb + 12288);
        ld16(gB  + kofs,         Lb + 16384);
        ld16(gB  + rstep + kofs, Lb + 20480);
    };

    // ---- ds_read offsets (ushort units within one 16KB tile)
    int aoff[4], boff[8];
#pragma unroll
    for (int i = 0; i < 4; i++) {
        int R = wr + i * 16 + l15;
        int p = R >> 1, c = ((R & 1) << 2) + quad;
        aoff[i] = p * 64 + ((c ^ (p & 7)) << 3);
    }
#pragma unroll
    for (int j = 0; j < 8; j++) {
        int R = wc + j * 16 + l15;
        int p = R >> 1, c = ((R & 1) << 2) + quad;
        boff[j] = p * 64 + ((c ^ (p & 7)) << 3);
    }

    stage(0, 0);                            // prologue: tile 0, 6 loads in flight
    int buf = 0;

    for (int kt = 0; kt < 32; ++kt) {
        // loads for tile kt were issued one full tile ago -> latency hidden
        asm volatile("s_waitcnt vmcnt(0)" ::: "memory");
        __builtin_amdgcn_s_barrier();       // raw barrier: no vmcnt drain beyond ours
        asm volatile("" ::: "memory");      // keep ds_reads below the barrier
        __builtin_amdgcn_sched_barrier(0);

        if (kt < 31) stage(buf ^ 1, (kt + 1) * 32);   // prefetch next tile

        const ushort_t* Lb = lds + buf * 24576;
        half8 ah[4], al[4], bf[4];
#pragma unroll
        for (int i = 0; i < 4; i++) {
            ah[i] = *(const half8*)(Lb + aoff[i]);
            al[i] = *(const half8*)(Lb + 8192 + aoff[i]);
        }
#pragma unroll
        for (int j = 0; j < 4; j++) bf[j] = *(const half8*)(Lb + 16384 + boff[j]);

        __builtin_amdgcn_s_setprio(1);
#pragma unroll
        for (int i = 0; i < 4; i++)
#pragma unroll
            for (int j = 0; j < 4; j++)
                acc[i][j] = __builtin_amdgcn_mfma_f32_16x16x32_f16(ah[i], bf[j], acc[i][j], 0, 0, 0);
#pragma unroll
        for (int i = 0; i < 4; i++)
#pragma unroll
            for (int j = 0; j < 4; j++)
                acc[i][j] = __builtin_amdgcn_mfma_f32_16x16x32_f16(al[i], bf[j], acc[i][j], 0, 0, 0);
        __builtin_amdgcn_s_setprio(0);

#pragma unroll
        for (int j = 0; j < 4; j++) bf[j] = *(const half8*)(Lb + 16384 + boff[4 + j]);

        __builtin_amdgcn_s_setprio(1);
#pragma unroll
        for (int i = 0; i < 4; i++)
#pragma unroll
            for (int j = 0; j < 4; j++)
                acc[i][4 + j] = __builtin_amdgcn_mfma_f32_16x16x32_f16(ah[i], bf[j], acc[i][4 + j], 0, 0, 0);
#pragma unroll
        for (int i = 0; i < 4; i++)
#pragma unroll
            for (int j = 0; j < 4; j++)
                acc[i][4 + j] = __builtin_amdgcn_mfma_f32_16x16x32_f16(al[i], bf[j], acc[i][4 + j], 0, 0, 0);
        __builtin_amdgcn_s_setprio(0);

        buf ^= 1;
    }

    // C store (f32, coalesced per 16 lanes)
#pragma unroll
    for (int i = 0; i < 4; i++) {
        int row_base = m0 + wr + i * 16 + quad * 4;
#pragma unroll
        for (int j = 0; j < 8; j++) {
            int col = n0 + wc + j * 16 + l15;
#pragma unroll
            for (int r = 0; r < 4; r++)
                C[(int64_t)(row_base + r) * N + col] = acc[i][j][r];
        }
    }

    // fused partial column stats (max & sumexp over this block's 256 rows)
    int wrow = wave >> 1;
#pragma unroll
    for (int j = 0; j < 8; j++) {
        float m = -3.0e38f;
#pragma unroll
        for (int i = 0; i < 4; i++)
#pragma unroll
            for (int r = 0; r < 4; r++) m = fmaxf(m, acc[i][j][r]);
        float s = 0.f;
#pragma unroll
        for (int i = 0; i < 4; i++)
#pragma unroll
            for (int r = 0; r < 4; r++) s += __expf(acc[i][j][r] - m);
#pragma unroll
        for (int d = 16; d <= 32; d <<= 1) {
            float m2 = __shfl_xor(m, d, 64);
            float s2 = __shfl_xor(s, d, 64);
            float nm = fmaxf(m, m2);
            s = s * __expf(m - nm) + s2 * __expf(m2 - nm);
            m = nm;
        }
        if (lane < 16) {
            red_m[wrow][wc + j * 16 + l15] = m;
            red_s[wrow][wc + j * 16 + l15] = s;
        }
    }
    __syncthreads();
    if (t < 256) {
        float m = red_m[0][t];
#pragma unroll
        for (int w = 1; w < 4; w++) m = fmaxf(m, red_m[w][t]);
        float s = 0.f;
#pragma unroll
        for (int w = 0; w < 4; w++) s += red_s[w][t] * __expf(red_m[w][t] - m);
        int idx = blockIdx.y * (B_ * S_) + b * S_ + n0 + t;
        pm[idx] = m;
        ps[idx] = s;
    }
}

// --------------------------- column softmax --------------------------------

__global__ void k_colstats2(const float* __restrict__ pm, const float* __restrict__ ps,
                            float* __restrict__ cmax, float* __restrict__ cinv)
{
    int i = blockIdx.x * 256 + threadIdx.x;   // 8192
    float m = -3.0e38f;
#pragma unroll
    for (int c = 0; c < 8; c++) m = fmaxf(m, pm[c * (B_ * S_) + i]);
    float sum = 0.f;
#pragma unroll
    for (int c = 0; c < 8; c++) sum += ps[c * (B_ * S_) + i] * __expf(pm[c * (B_ * S_) + i] - m);
    cmax[i] = m;
    cinv[i] = 1.0f / sum;
}

// weight = exp(L - cmax)/csum, in place; also emit f16 copy for the final GEMM
__global__ void k_softmax_norm(float4* __restrict__ L, const float4* __restrict__ cmax4,
                               const float4* __restrict__ cinv4, ushort4* __restrict__ wbf)
{
    const int64_t n4 = (int64_t)B_ * S_ * S_ / 4;
    for (int64_t i = (int64_t)blockIdx.x * blockDim.x + threadIdx.x; i < n4;
         i += (int64_t)gridDim.x * blockDim.x) {
        int b  = (int)(i >> 20);
        int c4 = (int)(i & 511);
        float4 x  = L[i];
        float4 cm = cmax4[b * 512 + c4];
        float4 ci = cinv4[b * 512 + c4];
        float4 w;
        w.x = __expf(x.x - cm.x) * ci.x;
        w.y = __expf(x.y - cm.y) * ci.y;
        w.z = __expf(x.z - cm.z) * ci.z;
        w.w = __expf(x.w - cm.w) * ci.w;
        L[i] = w;
        wbf[i] = (ushort4){f2h(w.x), f2h(w.y), f2h(w.z), f2h(w.w)};
    }
}

// --------------------- generic NT f16 GEMM, BK=64 --------------------------
// C[m][n] = sum_k A[m][k]*B[n][k], 128x128 tile, 4 waves, 16x16x32 f16 MFMA.
// XOR chunk swizzle: LDS chunk s of row r holds global chunk s ^ (r&7).
__launch_bounds__(256)
__global__ void k_gemm_nt_f16(const ushort_t* __restrict__ A, int lda, int64_t bsA,
                              const ushort_t* __restrict__ Bm, int ldb, int64_t bsB,
                              ushort_t* __restrict__ C, int ldc, int64_t bsC, int K)
{
    int b = blockIdx.z;
    A  += (int64_t)b * bsA;
    Bm += (int64_t)b * bsB;
    C  += (int64_t)b * bsC;

    __shared__ __align__(16) ushort_t sA[128 * 64], sB[128 * 64];

    int t    = threadIdx.x;
    int m0   = blockIdx.y * 128, n0 = blockIdx.x * 128;
    int wave = t >> 6, lane = t & 63;
    int wr   = (wave >> 1) * 64, wc = (wave & 1) * 64;
    int l15  = lane & 15, quad = lane >> 4;
    int e7   = l15 & 7;

    f32x4 acc[4][4];
#pragma unroll
    for (int i = 0; i < 4; i++)
#pragma unroll
        for (int j = 0; j < 4; j++) acc[i][j] = (f32x4){0.f, 0.f, 0.f, 0.f};

    int srow = t >> 3;                                // 0..31
    int scol = (((t & 7) ^ (srow & 7)) * 8);          // swizzled global chunk

    const ushort_t* gA = A  + (int64_t)(m0 + srow) * lda + scol;
    const ushort_t* gB = Bm + (int64_t)(n0 + srow) * ldb + scol;
    ushort_t* lA = sA + wave * 512;
    ushort_t* lB = sB + wave * 512;

    for (int k0 = 0; k0 < K; k0 += 64) {
#pragma unroll
        for (int j = 0; j < 4; j++) {
            ld16(gA + (int64_t)(j * 32) * lda + k0, lA + j * 2048);
            ld16(gB + (int64_t)(j * 32) * ldb + k0, lB + j * 2048);
        }
        __syncthreads();
#pragma unroll
        for (int ks = 0; ks < 64; ks += 32) {
            int gchunk = (ks >> 3) + quad;            // 0..7
            int slot   = (gchunk ^ e7) * 8;
            half8 af[4], bf[4];
#pragma unroll
            for (int i = 0; i < 4; i++)
                af[i] = *(const half8*)(&sA[(wr + i * 16 + l15) * 64 + slot]);
#pragma unroll
            for (int j = 0; j < 4; j++)
                bf[j] = *(const half8*)(&sB[(wc + j * 16 + l15) * 64 + slot]);
#pragma unroll
            for (int i = 0; i < 4; i++)
#pragma unroll
                for (int j = 0; j < 4; j++)
                    acc[i][j] = __builtin_amdgcn_mfma_f32_16x16x32_f16(af[i], bf[j], acc[i][j], 0, 0, 0);
        }
        __syncthreads();
    }

#pragma unroll
    for (int i = 0; i < 4; i++) {
        int row_base = m0 + wr + i * 16 + quad * 4;
#pragma unroll
        for (int j = 0; j < 4; j++) {
            int col = n0 + wc + j * 16 + l15;
#pragma unroll
            for (int r = 0; r < 4; r++)
                C[(int64_t)(row_base + r) * ldc + col] = f2h(acc[i][j][r]);
        }
    }
}

// --------------------------- final GEMM ------------------------------------
// out[b][t][n] = sum_s weight_f16[b][t][s]*PT[b][n][s] + Q[b][t][n] + bias[n]
// Same BK=64 structure + XOR chunk swizzle; f32 output with Q+bias epilogue.
__launch_bounds__(256)
__global__ void k_gemm_final(const ushort_t* __restrict__ Wt, const ushort_t* __restrict__ PT,
                             const ushort_t* __restrict__ Q, const float* __restrict__ bias,
                             float* __restrict__ out)
{
    const int K = S_, N = OUTD;
    int b = blockIdx.z;
    const ushort_t* A  = Wt + (int64_t)b * S_ * S_;
    const ushort_t* Bm = PT + (int64_t)b * OUTD * S_;
    const ushort_t* Qb = Q  + (int64_t)b * S_ * OUTD;
    float* Cb = out + (int64_t)b * S_ * OUTD;

    __shared__ __align__(16) ushort_t sA[128 * 64], sB[128 * 64];

    int t    = threadIdx.x;
    int m0   = blockIdx.y * 128, n0 = blockIdx.x * 128;
    int wave = t >> 6, lane = t & 63;
    int wr   = (wave >> 1) * 64, wc = (wave & 1) * 64;
    int l15  = lane & 15, quad = lane >> 4;
    int e7   = l15 & 7;

    f32x4 acc[4][4];
#pragma unroll
    for (int i = 0; i < 4; i++)
#pragma unroll
        for (int j = 0; j < 4; j++) acc[i][j] = (f32x4){0.f, 0.f, 0.f, 0.f};

    int srow = t >> 3;
    int scol = (((t & 7) ^ (srow & 7)) * 8);

    const ushort_t* gA = A  + (int64_t)(m0 + srow) * K + scol;
    const ushort_t* gB = Bm + (int64_t)(n0 + srow) * K + scol;
    ushort_t* lA = sA + wave * 512;
    ushort_t* lB = sB + wave * 512;

    for (int k0 = 0; k0 < K; k0 += 64) {
#pragma unroll
        for (int j = 0; j < 4; j++) {
            ld16(gA + (int64_t)(j * 32) * K + k0, lA + j * 2048);
            ld16(gB + (int64_t)(j * 32) * K + k0, lB + j * 2048);
        }
        __syncthreads();
#pragma unroll
        for (int ks = 0; ks < 64; ks += 32) {
            int gchunk = (ks >> 3) + quad;
            int slot   = (gchunk ^ e7) * 8;
            half8 af[4], bf[4];
#pragma unroll
            for (int i = 0; i < 4; i++)
                af[i] = *(const half8*)(&sA[(wr + i * 16 + l15) * 64 + slot]);
#pragma unroll
            for (int j = 0; j < 4; j++)
                bf[j] = *(const half8*)(&sB[(wc + j * 16 + l15) * 64 + slot]);
#pragma unroll
            for (int i = 0; i < 4; i++)
#pragma unroll
                for (int j = 0; j < 4; j++)
                    acc[i][j] = __builtin_amdgcn_mfma_f32_16x16x32_f16(af[i], bf[j], acc[i][j], 0, 0, 0);
        }
        __syncthreads();
    }

#pragma unroll
    for (int i = 0; i < 4; i++) {
        int row_base = m0 + wr + i * 16 + quad * 4;
#pragma unroll
        for (int j = 0; j < 4; j++) {
            int col = n0 + wc + j * 16 + l15;
            float bv = bias[col];
#pragma unroll
            for (int r = 0; r < 4; r++) {
                int64_t idx = (int64_t)(row_base + r) * N + col;
                Cb[idx] = acc[i][j][r] + h2f(Qb[idx]) + bv;
            }
        }
    }
}

// ------------------------------- launcher ----------------------------------

extern "C" void kernel_launch(void* const* d_in, const int* in_sizes, int n_in,
                              void* d_out, int out_size, void* d_ws, size_t ws_size,
                              hipStream_t stream)
{
    const float* src  = (const float*)d_in[0];
    const float* tgt  = (const float*)d_in[1];
    const float* W    = (const float*)d_in[2];
    const float* bias = (const float*)d_in[3];

    float* out = (float*)d_out;                           // [4,2048,1024]
    float* Lw  = out + (size_t)B_ * S_ * OUTD;            // [4,2048,2048] logits -> weight

    char*  ws = (char*)d_ws;
    size_t o  = 0;
    auto take = [&](size_t bytes) -> char* {
        char* p = ws + o;
        o += (bytes + 255) & ~(size_t)255;
        return p;
    };
    const size_t ELEMS = (size_t)B_ * S_ * D_;            // 8,388,608
    ushort_t* sh   = (ushort_t*)take(ELEMS * 2);          // src f16
    ushort_t* th   = (ushort_t*)take(ELEMS * 2);          // tgt hi f16
    ushort_t* tl   = (ushort_t*)take(ELEMS * 2);          // tgt lo f16
    ushort_t* wbf  = (ushort_t*)take((size_t)B_ * S_ * S_ * 2);     // weight f16
    ushort_t* wb   = (ushort_t*)take((size_t)OUTD * 2 * D_ * 2);    // W f16 [1024,2048]
    ushort_t* PT   = (ushort_t*)take((size_t)B_ * OUTD * S_ * 2);   // W1@src^T f16 [b,1024,2048]
    ushort_t* Qb   = (ushort_t*)take((size_t)B_ * S_ * OUTD * 2);   // tgt@W2^T f16 [b,2048,1024]
    float*    pm   = (float*)take(16 * (size_t)B_ * S_ * 4);
    float*    ps   = (float*)take(16 * (size_t)B_ * S_ * 4);
    float*    cmax = (float*)take((size_t)B_ * S_ * 4);
    float*    cinv = (float*)take((size_t)B_ * S_ * 4);
    (void)ws_size; (void)in_sizes; (void)n_in; (void)out_size;

    k_split<<<dim3(2048), dim3(256), 0, stream>>>((const float4*)src, (const float4*)tgt,
                                                  (ushort4*)sh, (ushort4*)th, (ushort4*)tl);
    k_wconv<<<dim3(512), dim3(256), 0, stream>>>((const float4*)W, (ushort4*)wb);

    // PT[b][n][s] = sum_d W1[n][d] * src[b][s][d]   (M=1024, N=2048, K=1024)
    k_gemm_nt_f16<<<dim3(16, 8, 4), dim3(256), 0, stream>>>(
        wb, 2 * D_, 0,
        sh, D_, (int64_t)S_ * D_,
        PT, S_, (int64_t)OUTD * S_, D_);

    // Q[b][t][n] = sum_d tgt[b][t][d] * W2[n][d]    (M=2048, N=1024, K=1024)
    k_gemm_nt_f16<<<dim3(8, 16, 4), dim3(256), 0, stream>>>(
        th, D_, (int64_t)S_ * D_,
        wb + D_, 2 * D_, 0,
        Qb, OUTD, (int64_t)S_ * OUTD, D_);

    k_gemm_logits<<<dim3(8, 8, 4), dim3(512), 0, stream>>>(th, tl, sh, Lw, pm, ps);

    k_colstats2<<<dim3(32), dim3(256), 0, stream>>>(pm, ps, cmax, cinv);
    k_softmax_norm<<<dim3(2048), dim3(256), 0, stream>>>((float4*)Lw, (const float4*)cmax,
                                                         (const float4*)cinv, (ushort4*)wbf);

    k_gemm_final<<<dim3(8, 16, 4), dim3(256), 0, stream>>>(wbf, PT, Qb, bias, out);
}

// Round 2
// 347.686 us; speedup vs baseline: 1.0695x; 1.0310x over previous
//
#include <hip/hip_runtime.h>
#include <stdint.h>

// ---------------------------------------------------------------------------
// Attention_18116172054662 on MI355X (gfx950)
//   L = tgt @ src^T  (2-term split-f16: (tgt_hi + tgt_lo) @ src_f16)
//   weight = softmax(L, axis=tgt)   -> second output (f32, in place in d_out)
//   out = weight @ PT^T + Q + b  where  PT = W1 @ src^T,  Q = tgt @ W2^T
// R1: global_load_lds width-16 staging, fused column stats, vectorized EW.
// R6: algebraic restructure (PT/Q/final), BK=64 GEMMs.
// R7: XOR chunk swizzle (slot = chunk ^ (row&7)) kills 128B-row bank wrap.
// R8: logits GEMM on 256x256 / 8-wave / dbuf-prefetch template:
//     raw s_barrier per K-tile, prefetch issued one tile ahead (vmcnt(0)
//     covers loads that had a full tile to land), paired-row LDS + XOR
//     swizzle (bank conflicts 6.3M -> 0), s_setprio around MFMA clusters.
//     logits 95 -> 83 us.
// R9: port the R8 structure to the remaining three GEMMs (PT, Q, final):
//     256x128 tile, BK=64, 8 waves 4x2 of 64x64, 96KB dbuf LDS, same
//     raw-barrier + 1-tile-deep prefetch + XOR swizzle + setprio.
//     Replaces the old 128x128 4-wave __syncthreads-drain kernels.
// ---------------------------------------------------------------------------

#define B_   4
#define S_   2048
#define D_   1024
#define OUTD 1024

typedef unsigned short ushort_t;
typedef _Float16 half8 __attribute__((ext_vector_type(8)));
typedef float    f32x4 __attribute__((ext_vector_type(4)));

__device__ __forceinline__ ushort_t f2h(float f) {
    union { _Float16 h; ushort_t u; } v;
    v.h = (_Float16)f;                    // RNE
    return v.u;
}
__device__ __forceinline__ float h2f(ushort_t u) {
    union { _Float16 h; ushort_t u; } v;
    v.u = u;
    return (float)v.h;
}

// async global->LDS, 16B per lane; LDS dest = wave-uniform base + lane*16
__device__ __forceinline__ void ld16(const ushort_t* g, ushort_t* l) {
    __builtin_amdgcn_global_load_lds(
        (const __attribute__((address_space(1))) void*)g,
        (__attribute__((address_space(3))) void*)l, 16, 0, 0);
}

// --------------------------- elementwise prep ------------------------------

// src -> f16; tgt -> f16 hi + f16 lo
__global__ void k_split(const float4* __restrict__ src, const float4* __restrict__ tgt,
                        ushort4* __restrict__ sh,
                        ushort4* __restrict__ th, ushort4* __restrict__ tl)
{
    const int64_t n4 = (int64_t)B_ * S_ * D_ / 4;
    for (int64_t i = (int64_t)blockIdx.x * blockDim.x + threadIdx.x; i < n4;
         i += (int64_t)gridDim.x * blockDim.x) {
        float4 s = src[i];
        sh[i] = (ushort4){f2h(s.x), f2h(s.y), f2h(s.z), f2h(s.w)};
        float4 tv = tgt[i];
        ushort4 ht = {f2h(tv.x), f2h(tv.y), f2h(tv.z), f2h(tv.w)};
        th[i] = ht;
        tl[i] = (ushort4){f2h(tv.x - h2f(ht.x)), f2h(tv.y - h2f(ht.y)),
                          f2h(tv.z - h2f(ht.z)), f2h(tv.w - h2f(ht.w))};
    }
}

__global__ void k_wconv(const float4* __restrict__ W, ushort4* __restrict__ wb)
{
    const int64_t n4 = (int64_t)OUTD * 2 * D_ / 4;
    for (int64_t i = (int64_t)blockIdx.x * blockDim.x + threadIdx.x; i < n4;
         i += (int64_t)gridDim.x * blockDim.x) {
        float4 w = W[i];
        wb[i] = (ushort4){f2h(w.x), f2h(w.y), f2h(w.z), f2h(w.w)};
    }
}

// ------------------------------- GEMM 1 ------------------------------------
// L[b] = tgt[b] @ src[b]^T, 2-term f16 split:  Ah*B + Al*B
// 256x256 tile, BK=32, 8 waves 4x2 of 64x128, 16x16x32 f16 MFMA.
// Double-buffered LDS, 1 s_barrier per K-tile, prefetch 1 tile deep.
// LDS layout per 256x32 tile: paired rows -> [128][64] f16, 128B lines,
//   chunk_g = (r&1)*4 + (k>>3); slot = chunk_g ^ ((r>>1)&7); 16B chunks.
// Epilogue: per-block (256-row chunk) column max/sumexp -> pm/ps (8 chunks).
__launch_bounds__(512, 2)
__global__ void k_gemm_logits(const ushort_t* __restrict__ Ah, const ushort_t* __restrict__ Al,
                              const ushort_t* __restrict__ Bs,
                              float* __restrict__ C,
                              float* __restrict__ pm, float* __restrict__ ps)
{
    const int M = S_, N = S_, K = D_;
    int b = blockIdx.z;
    Ah += (int64_t)b * M * K;  Al += (int64_t)b * M * K;
    Bs += (int64_t)b * N * K;
    C  += (int64_t)b * M * N;

    // dbuf: [2] x { Ah 16KB | Al 16KB | B 16KB }  (ushort units; 96 KiB total)
    __shared__ __align__(16) ushort_t lds[2 * 24576];
    __shared__ float red_m[4][256], red_s[4][256];

    int t    = threadIdx.x;                 // 0..511
    int m0   = blockIdx.y * 256, n0 = blockIdx.x * 256;
    int wave = t >> 6, lane = t & 63;
    int wr   = (wave >> 1) * 64;            // 0,64,128,192
    int wc   = (wave & 1) * 128;            // 0,128
    int l15  = lane & 15, quad = lane >> 4;

    f32x4 acc[4][8];
#pragma unroll
    for (int i = 0; i < 4; i++)
#pragma unroll
        for (int j = 0; j < 8; j++) acc[i][j] = (f32x4){0.f, 0.f, 0.f, 0.f};

    // ---- staging map: thread t writes LDS bytes [t*16, t*16+16) of each
    //      8KB pass (pass covers 64 paired-rows = 128 global rows).
    //      Invert the swizzle on the GLOBAL side; LDS dest stays linear.
    int pr   = t >> 3;                      // paired-row 0..63 within pass
    int slot = t & 7;
    int cg   = slot ^ (pr & 7);
    int srow = pr * 2 + (cg >> 2);          // 0..127 (+128 for pass 1)
    int scol = (cg & 3) * 8;                // f16 col within BK=32

    const ushort_t* gAh = Ah + (int64_t)(m0 + srow) * K + scol;
    const ushort_t* gAl = Al + (int64_t)(m0 + srow) * K + scol;
    const ushort_t* gB  = Bs + (int64_t)(n0 + srow) * K + scol;
    const int64_t rstep = (int64_t)128 * K;     // pass-1 global row offset

    auto stage = [&](int bufi, int kofs) {
        ushort_t* Lb = lds + bufi * 24576 + t * 8;
        ld16(gAh + kofs,         Lb);
        ld16(gAh + rstep + kofs, Lb + 4096);
        ld16(gAl + kofs,         Lb + 8192);
        ld16(gAl + rstep + kofs, Lb + 12288);
        ld16(gB  + kofs,         Lb + 16384);
        ld16(gB  + rstep + kofs, Lb + 20480);
    };

    // ---- ds_read offsets (ushort units within one 16KB tile)
    int aoff[4], boff[8];
#pragma unroll
    for (int i = 0; i < 4; i++) {
        int R = wr + i * 16 + l15;
        int p = R >> 1, c = ((R & 1) << 2) + quad;
        aoff[i] = p * 64 + ((c ^ (p & 7)) << 3);
    }
#pragma unroll
    for (int j = 0; j < 8; j++) {
        int R = wc + j * 16 + l15;
        int p = R >> 1, c = ((R & 1) << 2) + quad;
        boff[j] = p * 64 + ((c ^ (p & 7)) << 3);
    }

    stage(0, 0);                            // prologue: tile 0, 6 loads in flight
    int buf = 0;

    for (int kt = 0; kt < 32; ++kt) {
        // loads for tile kt were issued one full tile ago -> latency hidden
        asm volatile("s_waitcnt vmcnt(0)" ::: "memory");
        __builtin_amdgcn_s_barrier();       // raw barrier: no vmcnt drain beyond ours
        asm volatile("" ::: "memory");      // keep ds_reads below the barrier
        __builtin_amdgcn_sched_barrier(0);

        if (kt < 31) stage(buf ^ 1, (kt + 1) * 32);   // prefetch next tile

        const ushort_t* Lb = lds + buf * 24576;
        half8 ah[4], al[4], bf[4];
#pragma unroll
        for (int i = 0; i < 4; i++) {
            ah[i] = *(const half8*)(Lb + aoff[i]);
            al[i] = *(const half8*)(Lb + 8192 + aoff[i]);
        }
#pragma unroll
        for (int j = 0; j < 4; j++) bf[j] = *(const half8*)(Lb + 16384 + boff[j]);

        __builtin_amdgcn_s_setprio(1);
#pragma unroll
        for (int i = 0; i < 4; i++)
#pragma unroll
            for (int j = 0; j < 4; j++)
                acc[i][j] = __builtin_amdgcn_mfma_f32_16x16x32_f16(ah[i], bf[j], acc[i][j], 0, 0, 0);
#pragma unroll
        for (int i = 0; i < 4; i++)
#pragma unroll
            for (int j = 0; j < 4; j++)
                acc[i][j] = __builtin_amdgcn_mfma_f32_16x16x32_f16(al[i], bf[j], acc[i][j], 0, 0, 0);
        __builtin_amdgcn_s_setprio(0);

#pragma unroll
        for (int j = 0; j < 4; j++) bf[j] = *(const half8*)(Lb + 16384 + boff[4 + j]);

        __builtin_amdgcn_s_setprio(1);
#pragma unroll
        for (int i = 0; i < 4; i++)
#pragma unroll
            for (int j = 0; j < 4; j++)
                acc[i][4 + j] = __builtin_amdgcn_mfma_f32_16x16x32_f16(ah[i], bf[j], acc[i][4 + j], 0, 0, 0);
#pragma unroll
        for (int i = 0; i < 4; i++)
#pragma unroll
            for (int j = 0; j < 4; j++)
                acc[i][4 + j] = __builtin_amdgcn_mfma_f32_16x16x32_f16(al[i], bf[j], acc[i][4 + j], 0, 0, 0);
        __builtin_amdgcn_s_setprio(0);

        buf ^= 1;
    }

    // C store (f32, coalesced per 16 lanes)
#pragma unroll
    for (int i = 0; i < 4; i++) {
        int row_base = m0 + wr + i * 16 + quad * 4;
#pragma unroll
        for (int j = 0; j < 8; j++) {
            int col = n0 + wc + j * 16 + l15;
#pragma unroll
            for (int r = 0; r < 4; r++)
                C[(int64_t)(row_base + r) * N + col] = acc[i][j][r];
        }
    }

    // fused partial column stats (max & sumexp over this block's 256 rows)
    int wrow = wave >> 1;
#pragma unroll
    for (int j = 0; j < 8; j++) {
        float m = -3.0e38f;
#pragma unroll
        for (int i = 0; i < 4; i++)
#pragma unroll
            for (int r = 0; r < 4; r++) m = fmaxf(m, acc[i][j][r]);
        float s = 0.f;
#pragma unroll
        for (int i = 0; i < 4; i++)
#pragma unroll
            for (int r = 0; r < 4; r++) s += __expf(acc[i][j][r] - m);
#pragma unroll
        for (int d = 16; d <= 32; d <<= 1) {
            float m2 = __shfl_xor(m, d, 64);
            float s2 = __shfl_xor(s, d, 64);
            float nm = fmaxf(m, m2);
            s = s * __expf(m - nm) + s2 * __expf(m2 - nm);
            m = nm;
        }
        if (lane < 16) {
            red_m[wrow][wc + j * 16 + l15] = m;
            red_s[wrow][wc + j * 16 + l15] = s;
        }
    }
    __syncthreads();
    if (t < 256) {
        float m = red_m[0][t];
#pragma unroll
        for (int w = 1; w < 4; w++) m = fmaxf(m, red_m[w][t]);
        float s = 0.f;
#pragma unroll
        for (int w = 0; w < 4; w++) s += red_s[w][t] * __expf(red_m[w][t] - m);
        int idx = blockIdx.y * (B_ * S_) + b * S_ + n0 + t;
        pm[idx] = m;
        ps[idx] = s;
    }
}

// --------------------------- column softmax --------------------------------

__global__ void k_colstats2(const float* __restrict__ pm, const float* __restrict__ ps,
                            float* __restrict__ cmax, float* __restrict__ cinv)
{
    int i = blockIdx.x * 256 + threadIdx.x;   // 8192
    float m = -3.0e38f;
#pragma unroll
    for (int c = 0; c < 8; c++) m = fmaxf(m, pm[c * (B_ * S_) + i]);
    float sum = 0.f;
#pragma unroll
    for (int c = 0; c < 8; c++) sum += ps[c * (B_ * S_) + i] * __expf(pm[c * (B_ * S_) + i] - m);
    cmax[i] = m;
    cinv[i] = 1.0f / sum;
}

// weight = exp(L - cmax)/csum, in place; also emit f16 copy for the final GEMM
__global__ void k_softmax_norm(float4* __restrict__ L, const float4* __restrict__ cmax4,
                               const float4* __restrict__ cinv4, ushort4* __restrict__ wbf)
{
    const int64_t n4 = (int64_t)B_ * S_ * S_ / 4;
    for (int64_t i = (int64_t)blockIdx.x * blockDim.x + threadIdx.x; i < n4;
         i += (int64_t)gridDim.x * blockDim.x) {
        int b  = (int)(i >> 20);
        int c4 = (int)(i & 511);
        float4 x  = L[i];
        float4 cm = cmax4[b * 512 + c4];
        float4 ci = cinv4[b * 512 + c4];
        float4 w;
        w.x = __expf(x.x - cm.x) * ci.x;
        w.y = __expf(x.y - cm.y) * ci.y;
        w.z = __expf(x.z - cm.z) * ci.z;
        w.w = __expf(x.w - cm.w) * ci.w;
        L[i] = w;
        wbf[i] = (ushort4){f2h(w.x), f2h(w.y), f2h(w.z), f2h(w.w)};
    }
}

// ------------------ NT f16 GEMM, R8 structure (R9) --------------------------
// C[m][n] = sum_k A[m][k]*B[n][k].  256x128 tile, BK=64, 8 waves 4x2 of
// 64x64, 16x16x32 f16 MFMA.  Double-buffered LDS (96KB), 1 raw s_barrier
// per K-tile, prefetch 1 tile deep, XOR chunk swizzle (slot = chunk ^
// (row&7)) applied on the GLOBAL side for staging, on addresses for reads.
// LDS per tile: A 256x64 (32KB) @0, B 128x64 (16KB) @16384 (ushort units).
__launch_bounds__(512, 2)
__global__ void k_gemm_nt2(const ushort_t* __restrict__ A, int lda, int64_t bsA,
                           const ushort_t* __restrict__ Bm, int ldb, int64_t bsB,
                           ushort_t* __restrict__ C, int ldc, int64_t bsC, int K)
{
    int b = blockIdx.z;
    A  += (int64_t)b * bsA;
    Bm += (int64_t)b * bsB;
    C  += (int64_t)b * bsC;

    __shared__ __align__(16) ushort_t lds[2 * 24576];

    int t    = threadIdx.x;                 // 0..511
    int m0   = blockIdx.y * 256, n0 = blockIdx.x * 128;
    int wave = t >> 6, lane = t & 63;
    int wr   = (wave >> 1) * 64;            // 0,64,128,192
    int wc   = (wave & 1) * 64;             // 0,64
    int l15  = lane & 15, quad = lane >> 4;

    f32x4 acc[4][4];
#pragma unroll
    for (int i = 0; i < 4; i++)
#pragma unroll
        for (int j = 0; j < 4; j++) acc[i][j] = (f32x4){0.f, 0.f, 0.f, 0.f};

    // staging: thread t covers (row = srow + 64*pass, 16B chunk cg) where the
    // swizzle is inverted on the global side; LDS dest linear at t*16B/pass.
    int srow = t >> 3;                      // 0..63
    int cg   = (t & 7) ^ (srow & 7);
    int scol = cg * 8;

    const ushort_t* gA = A  + (int64_t)(m0 + srow) * lda + scol;
    const ushort_t* gB = Bm + (int64_t)(n0 + srow) * ldb + scol;

    auto stage = [&](int bufi, int k0) {
        ushort_t* Lb = lds + bufi * 24576 + t * 8;
        ld16(gA + k0,                        Lb);
        ld16(gA + (int64_t)64  * lda + k0,   Lb + 4096);
        ld16(gA + (int64_t)128 * lda + k0,   Lb + 8192);
        ld16(gA + (int64_t)192 * lda + k0,   Lb + 12288);
        ld16(gB + k0,                        Lb + 16384);
        ld16(gB + (int64_t)64  * ldb + k0,   Lb + 20480);
    };

    // read offsets (ushort units), h = K-half (ks = h*32)
    int aoff[4][2], boff[4][2];
#pragma unroll
    for (int i = 0; i < 4; i++) {
        int R = wr + i * 16 + l15;
#pragma unroll
        for (int h = 0; h < 2; h++) {
            int c = quad + h * 4;
            aoff[i][h] = R * 64 + ((c ^ (R & 7)) << 3);
        }
    }
#pragma unroll
    for (int j = 0; j < 4; j++) {
        int R = wc + j * 16 + l15;
#pragma unroll
        for (int h = 0; h < 2; h++) {
            int c = quad + h * 4;
            boff[j][h] = 16384 + R * 64 + ((c ^ (R & 7)) << 3);
        }
    }

    stage(0, 0);
    int buf = 0;
    const int NT = K >> 6;

    for (int kt = 0; kt < NT; ++kt) {
        asm volatile("s_waitcnt vmcnt(0)" ::: "memory");
        __builtin_amdgcn_s_barrier();
        asm volatile("" ::: "memory");
        __builtin_amdgcn_sched_barrier(0);

        if (kt + 1 < NT) stage(buf ^ 1, (kt + 1) * 64);

        const ushort_t* Lb = lds + buf * 24576;
#pragma unroll
        for (int h = 0; h < 2; h++) {
            half8 af[4], bf[4];
#pragma unroll
            for (int i = 0; i < 4; i++) af[i] = *(const half8*)(Lb + aoff[i][h]);
#pragma unroll
            for (int j = 0; j < 4; j++) bf[j] = *(const half8*)(Lb + boff[j][h]);
            __builtin_amdgcn_s_setprio(1);
#pragma unroll
            for (int i = 0; i < 4; i++)
#pragma unroll
                for (int j = 0; j < 4; j++)
                    acc[i][j] = __builtin_amdgcn_mfma_f32_16x16x32_f16(af[i], bf[j], acc[i][j], 0, 0, 0);
            __builtin_amdgcn_s_setprio(0);
        }
        buf ^= 1;
    }

#pragma unroll
    for (int i = 0; i < 4; i++) {
        int row_base = m0 + wr + i * 16 + quad * 4;
#pragma unroll
        for (int j = 0; j < 4; j++) {
            int col = n0 + wc + j * 16 + l15;
#pragma unroll
            for (int r = 0; r < 4; r++)
                C[(int64_t)(row_base + r) * ldc + col] = f2h(acc[i][j][r]);
        }
    }
}

// --------------------------- final GEMM (R9) --------------------------------
// out[b][t][n] = sum_s weight_f16[b][t][s]*PT[b][n][s] + Q[b][t][n] + bias[n]
// Same 256x128 / BK=64 / 8-wave dbuf structure; f32 out with Q+bias epilogue.
__launch_bounds__(512, 2)
__global__ void k_gemm_final(const ushort_t* __restrict__ Wt, const ushort_t* __restrict__ PT,
                             const ushort_t* __restrict__ Q, const float* __restrict__ bias,
                             float* __restrict__ out)
{
    const int K = S_, N = OUTD;
    int b = blockIdx.z;
    const ushort_t* A  = Wt + (int64_t)b * S_ * S_;
    const ushort_t* Bm = PT + (int64_t)b * OUTD * S_;
    const ushort_t* Qb = Q  + (int64_t)b * S_ * OUTD;
    float* Cb = out + (int64_t)b * S_ * OUTD;

    __shared__ __align__(16) ushort_t lds[2 * 24576];

    int t    = threadIdx.x;
    int m0   = blockIdx.y * 256, n0 = blockIdx.x * 128;
    int wave = t >> 6, lane = t & 63;
    int wr   = (wave >> 1) * 64;
    int wc   = (wave & 1) * 64;
    int l15  = lane & 15, quad = lane >> 4;

    f32x4 acc[4][4];
#pragma unroll
    for (int i = 0; i < 4; i++)
#pragma unroll
        for (int j = 0; j < 4; j++) acc[i][j] = (f32x4){0.f, 0.f, 0.f, 0.f};

    int srow = t >> 3;
    int cg   = (t & 7) ^ (srow & 7);
    int scol = cg * 8;

    const ushort_t* gA = A  + (int64_t)(m0 + srow) * K + scol;
    const ushort_t* gB = Bm + (int64_t)(n0 + srow) * K + scol;

    auto stage = [&](int bufi, int k0) {
        ushort_t* Lb = lds + bufi * 24576 + t * 8;
        ld16(gA + k0,                      Lb);
        ld16(gA + (int64_t)64  * K + k0,   Lb + 4096);
        ld16(gA + (int64_t)128 * K + k0,   Lb + 8192);
        ld16(gA + (int64_t)192 * K + k0,   Lb + 12288);
        ld16(gB + k0,                      Lb + 16384);
        ld16(gB + (int64_t)64  * K + k0,   Lb + 20480);
    };

    int aoff[4][2], boff[4][2];
#pragma unroll
    for (int i = 0; i < 4; i++) {
        int R = wr + i * 16 + l15;
#pragma unroll
        for (int h = 0; h < 2; h++) {
            int c = quad + h * 4;
            aoff[i][h] = R * 64 + ((c ^ (R & 7)) << 3);
        }
    }
#pragma unroll
    for (int j = 0; j < 4; j++) {
        int R = wc + j * 16 + l15;
#pragma unroll
        for (int h = 0; h < 2; h++) {
            int c = quad + h * 4;
            boff[j][h] = 16384 + R * 64 + ((c ^ (R & 7)) << 3);
        }
    }

    stage(0, 0);
    int buf = 0;
    const int NT = K >> 6;                  // 32

    for (int kt = 0; kt < NT; ++kt) {
        asm volatile("s_waitcnt vmcnt(0)" ::: "memory");
        __builtin_amdgcn_s_barrier();
        asm volatile("" ::: "memory");
        __builtin_amdgcn_sched_barrier(0);

        if (kt + 1 < NT) stage(buf ^ 1, (kt + 1) * 64);

        const ushort_t* Lb = lds + buf * 24576;
#pragma unroll
        for (int h = 0; h < 2; h++) {
            half8 af[4], bf[4];
#pragma unroll
            for (int i = 0; i < 4; i++) af[i] = *(const half8*)(Lb + aoff[i][h]);
#pragma unroll
            for (int j = 0; j < 4; j++) bf[j] = *(const half8*)(Lb + boff[j][h]);
            __builtin_amdgcn_s_setprio(1);
#pragma unroll
            for (int i = 0; i < 4; i++)
#pragma unroll
                for (int j = 0; j < 4; j++)
                    acc[i][j] = __builtin_amdgcn_mfma_f32_16x16x32_f16(af[i], bf[j], acc[i][j], 0, 0, 0);
            __builtin_amdgcn_s_setprio(0);
        }
        buf ^= 1;
    }

#pragma unroll
    for (int i = 0; i < 4; i++) {
        int row_base = m0 + wr + i * 16 + quad * 4;
#pragma unroll
        for (int j = 0; j < 4; j++) {
            int col = n0 + wc + j * 16 + l15;
            float bv = bias[col];
#pragma unroll
            for (int r = 0; r < 4; r++) {
                int64_t idx = (int64_t)(row_base + r) * N + col;
                Cb[idx] = acc[i][j][r] + h2f(Qb[idx]) + bv;
            }
        }
    }
}

// ------------------------------- launcher ----------------------------------

extern "C" void kernel_launch(void* const* d_in, const int* in_sizes, int n_in,
                              void* d_out, int out_size, void* d_ws, size_t ws_size,
                              hipStream_t stream)
{
    const float* src  = (const float*)d_in[0];
    const float* tgt  = (const float*)d_in[1];
    const float* W    = (const float*)d_in[2];
    const float* bias = (const float*)d_in[3];

    float* out = (float*)d_out;                           // [4,2048,1024]
    float* Lw  = out + (size_t)B_ * S_ * OUTD;            // [4,2048,2048] logits -> weight

    char*  ws = (char*)d_ws;
    size_t o  = 0;
    auto take = [&](size_t bytes) -> char* {
        char* p = ws + o;
        o += (bytes + 255) & ~(size_t)255;
        return p;
    };
    const size_t ELEMS = (size_t)B_ * S_ * D_;            // 8,388,608
    ushort_t* sh   = (ushort_t*)take(ELEMS * 2);          // src f16
    ushort_t* th   = (ushort_t*)take(ELEMS * 2);          // tgt hi f16
    ushort_t* tl   = (ushort_t*)take(ELEMS * 2);          // tgt lo f16
    ushort_t* wbf  = (ushort_t*)take((size_t)B_ * S_ * S_ * 2);     // weight f16
    ushort_t* wb   = (ushort_t*)take((size_t)OUTD * 2 * D_ * 2);    // W f16 [1024,2048]
    ushort_t* PT   = (ushort_t*)take((size_t)B_ * OUTD * S_ * 2);   // W1@src^T f16 [b,1024,2048]
    ushort_t* Qb   = (ushort_t*)take((size_t)B_ * S_ * OUTD * 2);   // tgt@W2^T f16 [b,2048,1024]
    float*    pm   = (float*)take(16 * (size_t)B_ * S_ * 4);
    float*    ps   = (float*)take(16 * (size_t)B_ * S_ * 4);
    float*    cmax = (float*)take((size_t)B_ * S_ * 4);
    float*    cinv = (float*)take((size_t)B_ * S_ * 4);
    (void)ws_size; (void)in_sizes; (void)n_in; (void)out_size;

    k_split<<<dim3(2048), dim3(256), 0, stream>>>((const float4*)src, (const float4*)tgt,
                                                  (ushort4*)sh, (ushort4*)th, (ushort4*)tl);
    k_wconv<<<dim3(512), dim3(256), 0, stream>>>((const float4*)W, (ushort4*)wb);

    // PT[b][n][s] = sum_d W1[n][d] * src[b][s][d]   (M=1024, N=2048, K=1024)
    k_gemm_nt2<<<dim3(16, 4, 4), dim3(512), 0, stream>>>(
        wb, 2 * D_, 0,
        sh, D_, (int64_t)S_ * D_,
        PT, S_, (int64_t)OUTD * S_, D_);

    // Q[b][t][n] = sum_d tgt[b][t][d] * W2[n][d]    (M=2048, N=1024, K=1024)
    k_gemm_nt2<<<dim3(8, 8, 4), dim3(512), 0, stream>>>(
        th, D_, (int64_t)S_ * D_,
        wb + D_, 2 * D_, 0,
        Qb, OUTD, (int64_t)S_ * OUTD, D_);

    k_gemm_logits<<<dim3(8, 8, 4), dim3(512), 0, stream>>>(th, tl, sh, Lw, pm, ps);

    k_colstats2<<<dim3(32), dim3(256), 0, stream>>>(pm, ps, cmax, cinv);
    k_softmax_norm<<<dim3(2048), dim3(256), 0, stream>>>((float4*)Lw, (const float4*)cmax,
                                                         (const float4*)cinv, (ushort4*)wbf);

    k_gemm_final<<<dim3(8, 8, 4), dim3(512), 0, stream>>>(wbf, PT, Qb, bias, out);
}